// Round 12
// baseline (6103.191 us; speedup 1.0000x reference)
//
#include <hip/hip_runtime.h>
#include <hip/hip_bf16.h>
#include <cstddef>

typedef unsigned short u16;
typedef short bf16x8 __attribute__((ext_vector_type(8)));   // 8 bf16 bit-patterns (4 VGPRs)
typedef float f32x4 __attribute__((ext_vector_type(4)));
typedef unsigned short u16x8 __attribute__((ext_vector_type(8)));
typedef unsigned short u16x4 __attribute__((ext_vector_type(4)));

#define MDIM 16384
#define NDIM 512
#define HPAD 520   // 512 + 8 elems: row stride 1040 B, breaks b128 bank alignment

__device__ __forceinline__ float b2f(u16 u) {
    return __uint_as_float(((unsigned int)u) << 16);
}
__device__ __forceinline__ u16 f2b(float f) {  // round-to-nearest-even
    unsigned int x = __float_as_uint(f);
    x += 0x7fffu + ((x >> 16) & 1u);
    return (u16)(x >> 16);
}
__device__ __forceinline__ float fast_tanh(float x) {
    // tanh(x) = 1 - 2/(e^{2x}+1); exp overflow -> +1, underflow -> -1 (correct limits)
    float e = __expf(2.0f * x);
    return 1.0f - 2.0f * __builtin_amdgcn_rcpf(e + 1.0f);
}

// ---------------------------------------------------------------------------
// Legacy tiled GEMM (input projection only).
// C(rows x 512) = A(rows x KDIM) * Bt(512 x KDIM)^T + bias(fp32)
// EPI 3: +addf (fp32), write Cf fp32 only        (projection -> state)
template <int KDIM, int EPI, bool AF32>
__global__ __launch_bounds__(256, 2) void gemm_bt(
    const void* __restrict__ Avoid, const u16* __restrict__ Bt,
    const float* __restrict__ bias, const float* __restrict__ addf,
    u16* __restrict__ Cb, float* __restrict__ Cf) {
    __shared__ u16 As[128 * 72];
    __shared__ u16 Bs[128 * 72];
    const int tid = threadIdx.x;
    const int m0 = blockIdx.y * 128;
    const int n0 = blockIdx.x * 128;
    const int lane = tid & 63;
    const int wave = tid >> 6;
    const int wm = (wave & 1) * 64;
    const int wn = (wave >> 1) * 64;
    const int lr = lane & 15;
    const int lk = (lane >> 4) * 8;

    f32x4 acc[4][4];
    f32x4 zero = {0.0f, 0.0f, 0.0f, 0.0f};
#pragma unroll
    for (int i = 0; i < 4; ++i)
#pragma unroll
        for (int j = 0; j < 4; ++j) acc[i][j] = zero;

    const int r0 = tid >> 3;
    const int c0 = (tid & 7) * 8;

    for (int kt = 0; kt < KDIM / 64; ++kt) {
        const int k0 = kt * 64;
#pragma unroll
        for (int it = 0; it < 4; ++it) {
            int r = it * 32 + r0;
            if constexpr (AF32) {
                const float* Af = (const float*)Avoid;
                const float* src = Af + (size_t)(m0 + r) * KDIM + k0 + c0;
                f32x4 lo = *(const f32x4*)(src);
                f32x4 hi = *(const f32x4*)(src + 4);
                u16x8 t;
#pragma unroll
                for (int q = 0; q < 4; ++q) { t[q] = f2b(lo[q]); t[q + 4] = f2b(hi[q]); }
                *(u16x8*)(&As[r * 72 + c0]) = t;
            } else {
                const u16* Ab = (const u16*)Avoid;
                *(f32x4*)(&As[r * 72 + c0]) =
                    *(const f32x4*)(Ab + (size_t)(m0 + r) * KDIM + k0 + c0);
            }
            *(f32x4*)(&Bs[r * 72 + c0]) =
                *(const f32x4*)(Bt + (size_t)(n0 + r) * KDIM + k0 + c0);
        }
        __syncthreads();
#pragma unroll
        for (int kk = 0; kk < 2; ++kk) {
            bf16x8 af[4], bw[4];
#pragma unroll
            for (int i = 0; i < 4; ++i) {
                af[i] = __builtin_bit_cast(
                    bf16x8, *(const f32x4*)(&As[(wm + i * 16 + lr) * 72 + kk * 32 + lk]));
                bw[i] = __builtin_bit_cast(
                    bf16x8, *(const f32x4*)(&Bs[(wn + i * 16 + lr) * 72 + kk * 32 + lk]));
            }
#pragma unroll
            for (int i = 0; i < 4; ++i)
#pragma unroll
                for (int j = 0; j < 4; ++j)
                    acc[i][j] = __builtin_amdgcn_mfma_f32_16x16x32_bf16(
                        af[i], bw[j], acc[i][j], 0, 0, 0);
        }
        __syncthreads();
    }
#pragma unroll
    for (int j = 0; j < 4; ++j) {
        const int col = n0 + wn + j * 16 + lr;
        const float bv = bias[col];
#pragma unroll
        for (int i = 0; i < 4; ++i) {
            const int rowb = m0 + wm + i * 16 + (lane >> 4) * 4;
#pragma unroll
            for (int r = 0; r < 4; ++r) {
                float v = acc[i][j][r] + bv;
                size_t off = (size_t)(rowb + r) * NDIM + col;
                if constexpr (EPI == 2) Cb[off] = f2b(v);
                if constexpr (EPI == 3) {
                    v += addf[off];
                    Cf[off] = v;
                }
            }
        }
    }
}

// ---------------------------------------------------------------------------
// On-chip dopri5 block solver, 64-row / 16-wave, weight-prefetch edition.
// 64 rows x 8 steps x 6 evals per block; 1024 threads (16 waves, each owns a
// 32-col strip of N=512). Fragment layout:
//   (i,j,r) <-> row = i*16 + (lane>>4)*4 + r, col = wn + j*16 + (lane&15)
//   with i=0..3 (64 rows), j=0..1 (32 cols), wn = wave*32. frag f = i*2+j.
// R10 post-mortem: weight-path L2 latency is the largest hideable cost;
// VGPR_Count was 64 at a 128 cap -> 64 regs of headroom. LAYER now runs a
// fully-unrolled 4-slot software pipeline: bw[kt+4] issues right after kt's
// MFMAs, keeping 8 weight loads in flight with ~400 cy of covering work.
// (+32 long-lived VGPRs -> ~110-125 total, still below the 128 cap.)
// - S: 32 fp32 regs/thread for the whole solve (read S32 once, OUT once).
// - K1..K5: block-local global scratch, fragment-packed [f][tid] u16x4
//   (off = f*4096 + tid*4 in a 32768-u16 slab) -> 512 B/wave contiguous;
//   same-thread RAW only (R4-R10-verified).
// - Activations: As/Hs ping-pong (133 KB LDS) -> 4 barriers/eval; 1 block/CU.
__global__ __launch_bounds__(1024, 4) void ode_block(
    const float* __restrict__ S32,
    const u16* __restrict__ W1t, const float* __restrict__ bb1,
    const u16* __restrict__ W2t, const float* __restrict__ bb2,
    const u16* __restrict__ W3t, const float* __restrict__ bb3,
    u16* __restrict__ K1g, u16* __restrict__ K2g, u16* __restrict__ K3g,
    u16* __restrict__ K4g, u16* __restrict__ K5g,
    float* __restrict__ OUT) {
    __shared__ u16 As[64 * HPAD];      // 66,560 B
    __shared__ u16 Hs[64 * HPAD];      // 66,560 B  (total 133,120 B)
    const int tid = threadIdx.x;
    const int lane = tid & 63;
    const int wn = (tid >> 6) * 32;    // wave's 32-col strip
    const int lr = lane & 15;
    const int lq = lane >> 4;          // 0..3
    const int lk = lq * 8;
    const size_t row0 = (size_t)blockIdx.x * 64;
    const int off4 = tid * 4;          // u16 offset inside a 4096-u16 frag slab
    u16* K1b = K1g + (size_t)blockIdx.x * 32768;
    u16* K2b = K2g + (size_t)blockIdx.x * 32768;
    u16* K3b = K3g + (size_t)blockIdx.x * 32768;
    u16* K4b = K4g + (size_t)blockIdx.x * 32768;
    u16* K5b = K5g + (size_t)blockIdx.x * 32768;

    constexpr double h = 0.1 / 8.0;
    constexpr float A21 = (float)(h * 1.0 / 5.0);
    constexpr float A31 = (float)(h * 3.0 / 40.0), A32 = (float)(h * 9.0 / 40.0);
    constexpr float A41 = (float)(h * 44.0 / 45.0), A42 = (float)(h * -56.0 / 15.0);
    constexpr float A43 = (float)(h * 32.0 / 9.0);
    constexpr float A51 = (float)(h * 19372.0 / 6561.0), A52 = (float)(h * -25360.0 / 2187.0);
    constexpr float A53 = (float)(h * 64448.0 / 6561.0), A54 = (float)(h * -212.0 / 729.0);
    constexpr float A61 = (float)(h * 9017.0 / 3168.0), A62 = (float)(h * -355.0 / 33.0);
    constexpr float A63 = (float)(h * 46732.0 / 5247.0), A64 = (float)(h * 49.0 / 176.0);
    constexpr float A65 = (float)(h * -5103.0 / 18656.0);
    constexpr float B1c = (float)(h * 35.0 / 384.0), B3c = (float)(h * 500.0 / 1113.0);
    constexpr float B4c = (float)(h * 125.0 / 192.0), B5c = (float)(h * -2187.0 / 6784.0);
    constexpr float B6c = (float)(h * 11.0 / 84.0);

    const f32x4 zf = {0.f, 0.f, 0.f, 0.f};

    // ---- persistent state in fragment layout (32 regs), f = i*2 + j
    float S[8][4];
#pragma unroll
    for (int f = 0; f < 8; ++f) {
        const int col = wn + (f & 1) * 16 + lr;
        const int rw = (f >> 1) * 16 + lq * 4;
#pragma unroll
        for (int r = 0; r < 4; ++r)
            S[f][r] = S32[(row0 + rw + r) * 512 + col];
    }

    f32x4 acc[4][2];

// stage: As(row-major LDS) = f2b(S + sum c_t * K_t), K's fragment-packed global
#define STAGE(NT, P0, P1, P2, P3, P4, C0, C1, C2, C3, C4)                          \
    do {                                                                           \
        _Pragma("unroll") for (int f = 0; f < 8; ++f) {                            \
            float sv[4];                                                           \
            _Pragma("unroll") for (int r = 0; r < 4; ++r) sv[r] = S[f][r];         \
            if ((NT) >= 1) {                                                       \
                u16x4 t = *(const u16x4*)((P0) + f * 4096 + off4);                 \
                _Pragma("unroll") for (int r = 0; r < 4; ++r)                      \
                    sv[r] += (C0) * b2f(t[r]);                                     \
            }                                                                      \
            if ((NT) >= 2) {                                                       \
                u16x4 t = *(const u16x4*)((P1) + f * 4096 + off4);                 \
                _Pragma("unroll") for (int r = 0; r < 4; ++r)                      \
                    sv[r] += (C1) * b2f(t[r]);                                     \
            }                                                                      \
            if ((NT) >= 3) {                                                       \
                u16x4 t = *(const u16x4*)((P2) + f * 4096 + off4);                 \
                _Pragma("unroll") for (int r = 0; r < 4; ++r)                      \
                    sv[r] += (C2) * b2f(t[r]);                                     \
            }                                                                      \
            if ((NT) >= 4) {                                                       \
                u16x4 t = *(const u16x4*)((P3) + f * 4096 + off4);                 \
                _Pragma("unroll") for (int r = 0; r < 4; ++r)                      \
                    sv[r] += (C3) * b2f(t[r]);                                     \
            }                                                                      \
            if ((NT) >= 5) {                                                       \
                u16x4 t = *(const u16x4*)((P4) + f * 4096 + off4);                 \
                _Pragma("unroll") for (int r = 0; r < 4; ++r)                      \
                    sv[r] += (C4) * b2f(t[r]);                                     \
            }                                                                      \
            const int col_ = wn + (f & 1) * 16 + lr;                               \
            const int rw_ = (f >> 1) * 16 + lq * 4;                                \
            As[(rw_ + 0) * HPAD + col_] = f2b(sv[0]);                              \
            As[(rw_ + 1) * HPAD + col_] = f2b(sv[1]);                              \
            As[(rw_ + 2) * HPAD + col_] = f2b(sv[2]);                              \
            As[(rw_ + 3) * HPAD + col_] = f2b(sv[3]);                              \
        }                                                                          \
    } while (0)

// load one kt's 2 weight fragments into BW (b128 from L2)
#define LD_BW2(BW, WT, KT)                                                         \
    {                                                                              \
        _Pragma("unroll") for (int j_ = 0; j_ < 2; ++j_)                           \
            BW[j_] = __builtin_bit_cast(bf16x8,                                    \
                *(const f32x4*)((WT) + (size_t)((wn + j_ * 16 + lr) << 9) +        \
                                (KT) * 32 + lk));                                  \
    }

// one pipelined kt step: af loads + 8 MFMAs with BW, then prefetch kt+4 into BW
#define LSTEP(SRC, WT, KT, BW)                                                     \
    {                                                                              \
        bf16x8 af[4];                                                              \
        _Pragma("unroll") for (int i_ = 0; i_ < 4; ++i_)                           \
            af[i_] = __builtin_bit_cast(bf16x8,                                    \
                *(const f32x4*)(&(SRC)[(i_ * 16 + lr) * HPAD + (KT) * 32 + lk]));  \
        _Pragma("unroll") for (int i_ = 0; i_ < 4; ++i_)                           \
            _Pragma("unroll") for (int j_ = 0; j_ < 2; ++j_)                       \
                acc[i_][j_] = __builtin_amdgcn_mfma_f32_16x16x32_bf16(             \
                    af[i_], BW[j_], acc[i_][j_], 0, 0, 0);                         \
        if ((KT) + 4 < 16) LD_BW2(BW, WT, (KT) + 4)                                \
    }

// one MLP layer: SRC(LDS) @ WT^T -> acc; 4-slot weight pipeline, fully unrolled
#define LAYER(SRC, WT)                                                             \
    do {                                                                           \
        _Pragma("unroll") for (int i_ = 0; i_ < 4; ++i_)                           \
            _Pragma("unroll") for (int j_ = 0; j_ < 2; ++j_) acc[i_][j_] = zf;     \
        bf16x8 bwS0[2], bwS1[2], bwS2[2], bwS3[2];                                 \
        LD_BW2(bwS0, WT, 0)                                                        \
        LD_BW2(bwS1, WT, 1)                                                        \
        LD_BW2(bwS2, WT, 2)                                                        \
        LD_BW2(bwS3, WT, 3)                                                        \
        LSTEP(SRC, WT, 0, bwS0)  LSTEP(SRC, WT, 1, bwS1)                           \
        LSTEP(SRC, WT, 2, bwS2)  LSTEP(SRC, WT, 3, bwS3)                           \
        LSTEP(SRC, WT, 4, bwS0)  LSTEP(SRC, WT, 5, bwS1)                           \
        LSTEP(SRC, WT, 6, bwS2)  LSTEP(SRC, WT, 7, bwS3)                           \
        LSTEP(SRC, WT, 8, bwS0)  LSTEP(SRC, WT, 9, bwS1)                           \
        LSTEP(SRC, WT, 10, bwS2) LSTEP(SRC, WT, 11, bwS3)                          \
        LSTEP(SRC, WT, 12, bwS0) LSTEP(SRC, WT, 13, bwS1)                          \
        LSTEP(SRC, WT, 14, bwS2) LSTEP(SRC, WT, 15, bwS3)                          \
    } while (0)

// tanh epilogue into DST (the other LDS buffer; no extra barrier needed)
#define EPI_TANH(BIAS, DST)                                                        \
    do {                                                                           \
        _Pragma("unroll") for (int j_ = 0; j_ < 2; ++j_) {                         \
            const float bv = (BIAS)[wn + j_ * 16 + lr];                            \
            _Pragma("unroll") for (int i_ = 0; i_ < 4; ++i_) {                     \
                const int rb = i_ * 16 + lq * 4;                                   \
                const int col_ = wn + j_ * 16 + lr;                                \
                _Pragma("unroll") for (int r_ = 0; r_ < 4; ++r_)                   \
                    (DST)[(rb + r_) * HPAD + col_] =                               \
                        f2b(fast_tanh(acc[i_][j_][r_] + bv));                      \
            }                                                                      \
        }                                                                          \
    } while (0)

// k epilogue: fragment-packed coalesced global store (same-thread slots)
#define EPI_K(DST)                                                                 \
    do {                                                                           \
        _Pragma("unroll") for (int i_ = 0; i_ < 4; ++i_)                           \
            _Pragma("unroll") for (int j_ = 0; j_ < 2; ++j_) {                     \
                const float bv = bb3[wn + j_ * 16 + lr];                           \
                u16x4 kv;                                                          \
                _Pragma("unroll") for (int r_ = 0; r_ < 4; ++r_)                   \
                    kv[r_] = f2b(acc[i_][j_][r_] + bv);                            \
                *(u16x4*)((DST) + (i_ * 2 + j_) * 4096 + off4) = kv;               \
            }                                                                      \
    } while (0)

// 3-layer MLP on staged As; leaves layer-3 pre-bias result in acc.
// Barriers: B1 (stage->L1), B2 (L1->L2), B3 (L2->L3), B4 (L3 reads drained).
#define MLP3                                                                       \
    __syncthreads();                                                               \
    LAYER(As, W1t);                                                                \
    EPI_TANH(bb1, Hs);                                                             \
    __syncthreads();                                                               \
    LAYER(Hs, W2t);                                                                \
    EPI_TANH(bb2, As);                                                             \
    __syncthreads();                                                               \
    LAYER(As, W3t);                                                                \
    __syncthreads();

#pragma clang loop unroll(disable)
    for (int st = 0; st < 8; ++st) {
        // e0: s1 = S -> k1
        STAGE(0, K1b, K1b, K1b, K1b, K1b, 0.f, 0.f, 0.f, 0.f, 0.f);
        MLP3;
        EPI_K(K1b);

        // e1: s2 = S + A21 k1 -> k2
        STAGE(1, K1b, K1b, K1b, K1b, K1b, A21, 0.f, 0.f, 0.f, 0.f);
        MLP3;
        EPI_K(K2b);

        // e2: s3 = S + A31 k1 + A32 k2 -> k3
        STAGE(2, K1b, K2b, K2b, K2b, K2b, A31, A32, 0.f, 0.f, 0.f);
        MLP3;
        EPI_K(K3b);

        // e3: s4 = S + A41 k1 + A42 k2 + A43 k3 -> k4
        STAGE(3, K1b, K2b, K3b, K3b, K3b, A41, A42, A43, 0.f, 0.f);
        MLP3;
        EPI_K(K4b);

        // e4: s5 = S + A51 k1 + A52 k2 + A53 k3 + A54 k4 -> k5
        STAGE(4, K1b, K2b, K3b, K4b, K4b, A51, A52, A53, A54, 0.f);
        MLP3;
        EPI_K(K5b);

        // e5: s6 = S + A61 k1 + A62 k2 + A63 k3 + A64 k4 + A65 k5 -> k6 (acc)
        STAGE(5, K1b, K2b, K3b, K4b, K5b, A61, A62, A63, A64, A65);
        MLP3;

        // fused state update: S += B1 k1 + B3 k3 + B4 k4 + B5 k5 + B6 k6
        // (k6 = acc + b3, re-rounded to bf16 -> matches prior verified numerics)
        {
            const bool last = (st == 7);
#pragma unroll
            for (int i = 0; i < 4; ++i)
#pragma unroll
                for (int j = 0; j < 2; ++j) {
                    const int f = i * 2 + j;
                    const float bv = bb3[wn + j * 16 + lr];
                    u16x4 t1 = *(const u16x4*)(K1b + f * 4096 + off4);
                    u16x4 t3 = *(const u16x4*)(K3b + f * 4096 + off4);
                    u16x4 t4 = *(const u16x4*)(K4b + f * 4096 + off4);
                    u16x4 t5 = *(const u16x4*)(K5b + f * 4096 + off4);
#pragma unroll
                    for (int r = 0; r < 4; ++r) {
                        const float k6 = b2f(f2b(acc[i][j][r] + bv));
                        S[f][r] += B1c * b2f(t1[r]) + B3c * b2f(t3[r]) +
                                   B4c * b2f(t4[r]) + B5c * b2f(t5[r]) + B6c * k6;
                    }
                    if (last) {
                        const int col = wn + j * 16 + lr;
                        const int rw = i * 16 + lq * 4;
#pragma unroll
                        for (int r = 0; r < 4; ++r)
                            OUT[(row0 + rw + r) * 512 + col] = S[f][r];
                    }
                }
        }
    }
#undef MLP3
#undef EPI_K
#undef EPI_TANH
#undef LAYER
#undef LSTEP
#undef LD_BW2
#undef STAGE
}

// out_bf16[c*R + r] = in_f32[r*Ncols + c]   (weight transpose + cast, tiny)
__global__ void transpose_k(const float* __restrict__ in, u16* __restrict__ out,
                            int R, int Ncols) {
    int idx = blockIdx.x * 256 + threadIdx.x;
    int r = idx / Ncols, c = idx % Ncols;
    out[(size_t)c * R + r] = f2b(in[idx]);
}

extern "C" void kernel_launch(void* const* d_in, const int* in_sizes, int n_in,
                              void* d_out, int out_size, void* d_ws, size_t ws_size,
                              hipStream_t stream) {
    // ---- order-robust input mapping via in_sizes ----
    const float *y = nullptr, *u_t = nullptr, *Wp = nullptr, *bp = nullptr;
    const float *W1 = nullptr, *b1 = nullptr, *W2 = nullptr, *b2 = nullptr;
    const float *W3 = nullptr, *b3 = nullptr;
    {
        const float* w262[3] = {nullptr, nullptr, nullptr};
        const float* s512[4] = {nullptr, nullptr, nullptr, nullptr};
        int i512[4] = {0, 0, 0, 0};
        int n262 = 0, n512 = 0;
        for (int i = 0; i < n_in; ++i) {
            const float* p = (const float*)d_in[i];
            int sz = in_sizes[i];
            if (sz == MDIM * NDIM) y = p;
            else if (sz == MDIM * 256) u_t = p;
            else if (sz == 256 * 512) Wp = p;
            else if (sz == 512 * 512) { if (n262 < 3) w262[n262++] = p; }
            else if (sz == 512) { if (n512 < 4) { i512[n512] = i; s512[n512++] = p; } }
        }
        W1 = w262[0]; W2 = w262[1]; W3 = w262[2];
        bool contig = (n512 == 4) && (i512[3] == i512[0] + 3);
        if (contig) { b1 = s512[0]; b2 = s512[1]; b3 = s512[2]; bp = s512[3]; }
        else        { bp = s512[0]; b1 = s512[1]; b2 = s512[2]; b3 = s512[3]; }
        if (!y || !u_t || !Wp || !W1 || n512 < 4) {  // fallback: dict order
            y  = (const float*)d_in[0]; u_t = (const float*)d_in[1];
            Wp = (const float*)d_in[2]; bp  = (const float*)d_in[3];
            W1 = (const float*)d_in[4]; b1  = (const float*)d_in[5];
            W2 = (const float*)d_in[6]; b2  = (const float*)d_in[7];
            W3 = (const float*)d_in[8]; b3  = (const float*)d_in[9];
        }
    }

    u16* ws  = (u16*)d_ws;
    u16* Wpt = ws;                    // 512x256 bf16  (N x K, K contiguous)
    u16* W1t = Wpt + 512 * 256;       // 512x512 bf16
    u16* W2t = W1t + 512 * 512;
    u16* W3t = W2t + 512 * 512;
    const size_t wfix = 512 * 256 + 3 * 512 * 512;   // 917504 u16 = 1.84 MB

    // per-row workspace: S32 fp32 (1024 u16) + K1..K5 fragment-packed (5*512 u16)
    long wsElems = (long)(ws_size / 2);
    long chunk = (wsElems - (long)wfix) / (7L * NDIM);
    chunk = (chunk / 128) * 128;
    if (chunk > MDIM) chunk = MDIM;
    if (chunk < 128) chunk = 128;

    transpose_k<<<512, 256, 0, stream>>>(Wp, Wpt, 256, 512);
    transpose_k<<<1024, 256, 0, stream>>>(W1, W1t, 512, 512);
    transpose_k<<<1024, 256, 0, stream>>>(W2, W2t, 512, 512);
    transpose_k<<<1024, 256, 0, stream>>>(W3, W3t, 512, 512);

    float* OUT = (float*)d_out;   // fp32 output, per reference dtype

    for (long row0 = 0; row0 < MDIM; row0 += chunk) {
        const long rows = (MDIM - row0 < chunk) ? (MDIM - row0) : chunk;
        const size_t CB = (size_t)rows * NDIM;

        u16* base = ws + wfix;
        float* S32 = (float*)base;          // 2*CB u16
        u16* K1g = base + 2 * CB;           // CB u16 each (rows/64 blocks x 32768)
        u16* K2g = base + 3 * CB;
        u16* K3g = base + 4 * CB;
        u16* K4g = base + 5 * CB;
        u16* K5g = base + 6 * CB;

        // S32 = u_t @ Wp + bp + y  (fp32 only)
        dim3 gg(4, (unsigned)(rows / 128));
        gemm_bt<256, 3, true><<<gg, 256, 0, stream>>>(
            (const void*)(u_t + (size_t)row0 * 256), Wpt, bp,
            y + (size_t)row0 * NDIM, nullptr, S32);

        // whole 8-step solve on-chip per 64-row block; 1 block/CU, 16 waves
        const int nb = (int)(rows / 64);
        ode_block<<<nb, 1024, 0, stream>>>(
            S32, W1t, b1, W2t, b2, W3t, b3,
            K1g, K2g, K3g, K4g, K5g, OUT + (size_t)row0 * NDIM);
    }
}